// Round 3
// baseline (12808.353 us; speedup 1.0000x reference)
//
#include <hip/hip_runtime.h>
#include <cmath>

// ---------------- problem constants ----------------
#define BZ    32
#define NP    196
#define DDIM  768
#define NHEAD 12
#define MDIM  192
#define NLAY  6
#define FFDIM 3072
#define HEADU 512
#define NCLS  1000
#define KHEAD 150528      // NP*DDIM
#define BND   4816896     // BZ*NP*DDIM

typedef __bf16 bf16_t;
typedef __bf16 bf16x8 __attribute__((ext_vector_type(8)));
typedef __bf16 bf16x4 __attribute__((ext_vector_type(4)));
typedef float  f32x4  __attribute__((ext_vector_type(4)));

// ---------------- workspace layout (BYTE offsets) ----------------
#define OB_X      0L            // fp32 residual           19,267,584
#define OB_R      19267584L     // fp32 x2                 19,267,584
#define OB_XB     38535168L     // bf16 LN out              9,633,792
#define OB_QKV    48168960L     // bf16 Q,K head-major     57,802,752 (+4K slack)
#define OB_VT     105975808L    // bf16 V^T [384][192][208] 30,670,848
#define OB_O      136646656L    // bf16 o [6144][2368]     29,097,984
#define OB_TF32   165744640L    // fp32 t partial           4,816,896
#define OB_T      170561536L    // bf16 t [6272? 32*196][192] 2,412,544
#define OB_H1     172974080L    // bf16 FFN hidden (alias PATB) 38,535,168
#define OB_WQKV   211509248L    // bf16 [6912][768]        10,616,832
#define OB_WO1    222126080L    // bf16 [256][2368]         1,212,416
#define OB_WO2    223338496L    // bf16 [768][192]            294,912
#define OB_WD1    223633408L    // bf16 [3072][768]         4,718,592
#define OB_WD2    228352000L    // bf16 [768][3072]         4,718,592
#define OB_WPAT   233070592L    // bf16 [768][768]          1,179,648
#define OB_BQKV   234250240L    // fp32 [6912]                 27,648
#define OB_RED    234277888L
#define OB_STAT   234286080L
#define OB_FEAT   234286336L

#define QKV_GSTRIDE 14450688L   // elements per Q/K region
#define VT_SSTRIDE  39936L      // 192*208 elements per slab
#define ATTN_LDSP   93184       // P area start (K/V area = 208*448)
#define ATTN_LDS    143360      // total dynamic LDS bytes

__device__ __forceinline__ float gelu_exact(float x){
    return 0.5f * x * (1.0f + erff(x * 0.70710678118654752f));
}

__device__ __forceinline__ void gld16(const void* g, void* l){
    __builtin_amdgcn_global_load_lds((const __attribute__((address_space(1))) void*)g,
                                     (__attribute__((address_space(3))) void*)l, 16, 0, 0);
}

// ---------------- patch extraction (fp32 -> bf16) ----------------
__global__ void __launch_bounds__(256)
patch_extract_k(const float* __restrict__ img, bf16_t* __restrict__ out)
{
    long idx = (long)blockIdx.x * 256 + threadIdx.x;
    if (idx >= (long)BND) return;
    int k = (int)(idx % DDIM);
    long bn = idx / DDIM;
    int n = (int)(bn % NP);
    int b = (int)(bn / NP);
    int c  = k % 3;
    int pj = (k / 3) % 16;
    int pi = k / 48;
    int gi = n / 14, gj = n % 14;
    long src = (((long)(b * 224 + gi * 16 + pi)) * 224 + (gj * 16 + pj)) * 3 + c;
    out[idx] = (bf16_t)img[src];
}

// ---------------- weight convert+transpose fp32->bf16 ----------------
__global__ void __launch_bounds__(256)
wconv_k(const float* __restrict__ in, bf16_t* __restrict__ out,
        int IR, int IC, long OLD, int perm, int padTo)
{
    __shared__ float tile[32][33];
    int tid = threadIdx.x, tx = tid & 31, ty = tid >> 5;
    int c0 = blockIdx.x * 32, r0 = blockIdx.y * 32;
    #pragma unroll
    for (int i = 0; i < 4; i++){
        int r = r0 + ty + 8*i, c = c0 + tx;
        tile[ty + 8*i][tx] = (r < IR && c < IC) ? in[(long)r * IC + c] : 0.f;
    }
    __syncthreads();
    #pragma unroll
    for (int i = 0; i < 4; i++){
        int c = c0 + ty + 8*i, r = r0 + tx;
        if (c < IC && r < padTo){
            long pc = perm ? (long)(c % 12) * 192 + c / 12 : (long)c;
            out[pc * OLD + r] = (bf16_t)tile[tx][ty + 8*i];
        }
    }
}

// ---------------- gather QKV bias into [6912] (g-major, h*192+m order) --------
__global__ void __launch_bounds__(256)
gather_bias_k(const float* __restrict__ qb, const float* __restrict__ kb,
              const float* __restrict__ vb, float* __restrict__ out)
{
    int tid = blockIdx.x * 256 + threadIdx.x;
    if (tid >= 6912) return;
    int g = tid / 2304, w = tid % 2304;
    int h = w / 192, m = w % 192;
    const float* src = (g == 0) ? qb : (g == 1) ? kb : vb;
    out[tid] = src[m * 12 + h];
}

// ---------------- pad zero kernels ----------------
__global__ void __launch_bounds__(256)
zero_pad_o_k(bf16_t* __restrict__ o)
{
    int idx = blockIdx.x * 256 + threadIdx.x;
    if (idx >= 6144*16) return;
    int r = idx >> 4, j = idx & 15;
    o[(long)r * 2368 + 2352 + j] = (bf16_t)0.f;
}

__global__ void __launch_bounds__(256)
vt_pad_k(bf16_t* __restrict__ vt)
{
    int idx = blockIdx.x * 256 + threadIdx.x;
    if (idx >= 73728*12) return;
    int r = idx / 12, j = idx % 12;
    vt[(long)r * 208 + 196 + j] = (bf16_t)0.f;
}

// ---------------- global layernorm ----------------
__global__ void __launch_bounds__(256)
reduce_k(const float* __restrict__ x, float* __restrict__ psum, float* __restrict__ psq)
{
    __shared__ float ss[256], sq[256];
    float s = 0.f, q = 0.f;
    const long n4 = BND / 4;
    const float4* x4 = (const float4*)x;
    for (long i = (long)blockIdx.x * 256 + threadIdx.x; i < n4; i += (long)gridDim.x * 256){
        float4 v = x4[i];
        s += v.x + v.y + v.z + v.w;
        q += v.x*v.x + v.y*v.y + v.z*v.z + v.w*v.w;
    }
    ss[threadIdx.x] = s; sq[threadIdx.x] = q;
    __syncthreads();
    for (int st = 128; st > 0; st >>= 1){
        if (threadIdx.x < st){ ss[threadIdx.x] += ss[threadIdx.x+st]; sq[threadIdx.x] += sq[threadIdx.x+st]; }
        __syncthreads();
    }
    if (threadIdx.x == 0){ psum[blockIdx.x] = ss[0]; psq[blockIdx.x] = sq[0]; }
}

__global__ void __launch_bounds__(256)
stats_k(const float* __restrict__ psum, const float* __restrict__ psq, float* __restrict__ stats)
{
    __shared__ float ss[256], sq[256];
    float s = 0.f, q = 0.f;
    for (int i = threadIdx.x; i < 1024; i += 256){ s += psum[i]; q += psq[i]; }
    ss[threadIdx.x] = s; sq[threadIdx.x] = q;
    __syncthreads();
    for (int st = 128; st > 0; st >>= 1){
        if (threadIdx.x < st){ ss[threadIdx.x] += ss[threadIdx.x+st]; sq[threadIdx.x] += sq[threadIdx.x+st]; }
        __syncthreads();
    }
    if (threadIdx.x == 0){
        float mean = ss[0] / (float)BND;
        float var  = sq[0] / (float)BND - mean * mean;
        stats[0] = mean;
        stats[1] = rsqrtf(var + 1e-6f);
    }
}

__global__ void __launch_bounds__(256)
ln_apply_k(const float* __restrict__ x, bf16_t* __restrict__ yb, float* __restrict__ yf,
           const float* __restrict__ stats)
{
    long i = (long)blockIdx.x * 256 + threadIdx.x;
    if (i >= BND / 4) return;
    float mean = stats[0], inv = stats[1];
    float4 v = ((const float4*)x)[i];
    v.x = (v.x - mean) * inv;
    v.y = (v.y - mean) * inv;
    v.z = (v.z - mean) * inv;
    v.w = (v.w - mean) * inv;
    bf16x4 o4 = { (bf16_t)v.x, (bf16_t)v.y, (bf16_t)v.z, (bf16_t)v.w };
    ((bf16x4*)yb)[i] = o4;
    if (yf) ((float4*)yf)[i] = v;
}

// ---------------- fused attention: one block per (qhalf, slab) ----------------
// Qh/Kh: [384][196][192] bf16;  VT: [384][192][208] bf16 (cols 196..207 zero)
// O: [6144][2368] bf16, write o[b*192+m][h*196+n]
__global__ void __launch_bounds__(256)
attn_fused_k(const bf16_t* __restrict__ Qh, const bf16_t* __restrict__ Kh,
             const bf16_t* __restrict__ VT, bf16_t* __restrict__ O)
{
    extern __shared__ char lds[];
    const int tid = threadIdx.x, lane = tid & 63, w = tid >> 6;
    const int fr = lane & 15, kc = lane >> 4;
    const int s = blockIdx.y, qhalf = blockIdx.x;
    const int q0 = qhalf * 112;
    const int b = s & 31, h = s >> 5;
    const float scale = 0.03608439182435161f;   // 1/sqrt(768)
    const char* Qs = (const char*)(Qh + (long)s * 37632);
    const char* Ks = (const char*)(Kh + (long)s * 37632);
    const char* Vs = (const char*)(VT + (long)s * VT_SSTRIDE);

    // ---- stage K: rows n'=0..195, 384B payload per 448B row, src pre-swizzled
    for (int t = 0; t < 23; t++){
        int idx = t*256 + tid;
        if (idx < 5824){
            int row = idx / 28, sl = idx - row*28;
            bool val = (sl < 24) && (row < 196);
            const char* src = Ks + (val ? (row*384 + ((sl*16) ^ ((row & 7) << 4))) : 0);
            gld16(src, lds + idx*16);
        }
    }
    asm volatile("s_waitcnt vmcnt(0)");
    __syncthreads();

    float pv_all[2][13][4];
    // ---- phase 1: S = Q K^T, softmax -> P (regs), per-wave frags {w, w+4}
    #pragma unroll
    for (int ii = 0; ii < 2; ii++){
        int i = w + ii*4;
        if (i >= 7) continue;
        f32x4 sa[13];
        #pragma unroll
        for (int f = 0; f < 13; f++) sa[f] = (f32x4){0.f,0.f,0.f,0.f};
        int qr = q0 + i*16 + fr; if (qr > 195) qr = 195;
        #pragma unroll
        for (int c = 0; c < 6; c++){
            bf16x8 av = *(const bf16x8*)(Qs + (long)qr*384 + c*64 + kc*16);
            #pragma unroll
            for (int f = 0; f < 13; f++){
                int krow = f*16 + fr;
                bf16x8 bv = *(const bf16x8*)(lds + krow*448 + ((c*64 + kc*16) ^ ((krow & 7) << 4)));
                sa[f] = __builtin_amdgcn_mfma_f32_16x16x32_bf16(av, bv, sa[f], 0, 0, 0);
            }
        }
        #pragma unroll
        for (int r = 0; r < 4; r++){
            float mx = -1e30f;
            #pragma unroll
            for (int f = 0; f < 13; f++)
                if (f*16 + fr < 196) mx = fmaxf(mx, sa[f][r] * scale);
            mx = fmaxf(mx, __shfl_xor(mx, 1));
            mx = fmaxf(mx, __shfl_xor(mx, 2));
            mx = fmaxf(mx, __shfl_xor(mx, 4));
            mx = fmaxf(mx, __shfl_xor(mx, 8));
            float sum = 0.f;
            #pragma unroll
            for (int f = 0; f < 13; f++){
                float pv = (f*16 + fr < 196) ? __expf(sa[f][r] * scale - mx) : 0.f;
                pv_all[ii][f][r] = pv; sum += pv;
            }
            sum += __shfl_xor(sum, 1);
            sum += __shfl_xor(sum, 2);
            sum += __shfl_xor(sum, 4);
            sum += __shfl_xor(sum, 8);
            float inv = 1.f / sum;
            #pragma unroll
            for (int f = 0; f < 13; f++) pv_all[ii][f][r] *= inv;
        }
        // write P to LDS (swizzled), rows 16i..16i+15
        #pragma unroll
        for (int f = 0; f < 13; f++)
            #pragma unroll
            for (int r = 0; r < 4; r++){
                int row = i*16 + kc*4 + r;
                int cb = (f*16 + fr) * 2;
                int a = ATTN_LDSP + row*448 + (cb < 384 ? (cb ^ ((row & 7) << 4)) : cb);
                *(bf16_t*)(lds + a) = (bf16_t)pv_all[ii][f][r];
            }
        // zero P tail bytes 416..447 of these rows
        if (lane < 32){
            int row = i*16 + (lane >> 1);
            *(f32x4*)(lds + ATTN_LDSP + row*448 + 416 + (lane & 1)*16) = (f32x4){0.f,0.f,0.f,0.f};
        }
    }
    __syncthreads();

    // ---- stage V^T: rows m=0..191, 416B payload per 448B row
    for (int t = 0; t < 21; t++){
        int idx = t*256 + tid;
        int row = idx / 28, sl = idx - row*28;
        bool val = (sl < 26);
        int cb = (sl < 24) ? ((sl*16) ^ ((row & 7) << 4)) : sl*16;
        const char* src = Vs + (val ? (row*416 + cb) : 0);
        gld16(src, lds + idx*16);
    }
    asm volatile("s_waitcnt vmcnt(0)");
    __syncthreads();

    // ---- phase 2: O = P V^T
    #pragma unroll
    for (int ii = 0; ii < 2; ii++){
        int i = w + ii*4;
        if (i >= 7) continue;
        f32x4 oa[12];
        #pragma unroll
        for (int f = 0; f < 12; f++) oa[f] = (f32x4){0.f,0.f,0.f,0.f};
        #pragma unroll
        for (int c = 0; c < 7; c++){
            int prow = i*16 + fr;
            int cb = c*64 + kc*16;
            int acb = (cb < 384) ? (cb ^ ((prow & 7) << 4)) : cb;
            bf16x8 av = *(const bf16x8*)(lds + ATTN_LDSP + prow*448 + acb);
            #pragma unroll
            for (int f = 0; f < 12; f++){
                int vrow = f*16 + fr;
                int bcb = (cb < 384) ? (cb ^ ((vrow & 7) << 4)) : cb;
                bf16x8 bv = *(const bf16x8*)(lds + vrow*448 + bcb);
                oa[f] = __builtin_amdgcn_mfma_f32_16x16x32_bf16(av, bv, oa[f], 0, 0, 0);
            }
        }
        #pragma unroll
        for (int f = 0; f < 12; f++){
            int m = f*16 + fr;
            #pragma unroll
            for (int r = 0; r < 4; r++){
                int n = q0 + i*16 + kc*4 + r;
                if (n < 196)
                    O[((long)(b*192 + m))*2368 + h*196 + n] = (bf16_t)oa[f][r];
            }
        }
    }
}

// ---------------- MFMA bf16 GEMM: 128x128 tile, BK=32, 4 waves ----------------
// A,B TN (k-contiguous). modes: 0 f32 rowmajor(+Cadd), 1 bf16 rowmajor,
// 2 QKV scatter (Caux=VT), 5 split-K atomic into f32 C
__global__ void __launch_bounds__(256)
mfma_gemm_k(const bf16_t* __restrict__ A, long ldA, long sA,
            const bf16_t* __restrict__ B, long ldB, long sB,
            void* __restrict__ C, long ldC, long sC, void* __restrict__ Caux,
            const float* __restrict__ Cadd,
            const float* __restrict__ bias1,
            const float* __restrict__ bias2, int b2mod, int b2ld,
            int Md, int Nd, int Kd, float alpha, int doGelu, int mode)
{
    __shared__ bf16_t sm[2][2][128][32];   // 32 KiB
    const int tid = threadIdx.x;
    const int lane = tid & 63, w = tid >> 6;
    const int wm = w >> 1, wn = w & 1;
    const int z = blockIdx.z;
    const int row0 = blockIdx.y * 128, col0 = blockIdx.x * 128;

    long kStart = 0; int KdL = Kd; long zA = z, zC = z;
    if (mode == 5){ kStart = (z < 2) ? z*608 : 1216 + (long)(z-2)*576; KdL = (z < 2) ? 608 : 576; zA = 0; zC = 0; }

    const bf16_t* Ab = A + zA * sA + (long)row0 * ldA + kStart;
    const bf16_t* Bb = B + zA * sB + (long)col0 * ldB + kStart;

    f32x4 acc[4][4];
    #pragma unroll
    for (int i = 0; i < 4; i++)
        #pragma unroll
        for (int j = 0; j < 4; j++)
            acc[i][j] = (f32x4){0.f, 0.f, 0.f, 0.f};

    const int fr = lane & 15, kc = lane >> 4;
    const int swz = (fr >> 1) & 3;
    int aOff[4], bOff[4];
    #pragma unroll
    for (int i = 0; i < 4; i++){
        aOff[i] = (wm*64 + i*16 + fr) * 64 + ((kc ^ swz) << 4);
        bOff[i] = (wn*64 + i*16 + fr) * 64 + ((kc ^ swz) << 4);
    }

    auto stage = [&](int buf, int kt){
        long kOff = (long)kt * 32;
        #pragma unroll
        for (int r = 0; r < 2; r++){
            int idx = r*256 + tid;
            int row = idx >> 2, cp = idx & 3;
            int cc = cp ^ ((row >> 1) & 3);
            gld16((const void*)(Ab + (long)row*ldA + kOff + cc*8), (void*)&sm[buf][0][row][cp*8]);
            gld16((const void*)(Bb + (long)row*ldB + kOff + cc*8), (void*)&sm[buf][1][row][cp*8]);
        }
    };

    const int nt = KdL >> 5;
    stage(0, 0);
    __syncthreads();
    int cur = 0;
    for (int t = 0; t < nt; t++){
        if (t + 1 < nt) stage(cur ^ 1, t + 1);
        const char* baseA = (const char*)sm + cur * 16384;
        const char* baseB = baseA + 8192;
        bf16x8 av[4], bv[4];
        #pragma unroll
        for (int i = 0; i < 4; i++){
            av[i] = *(const bf16x8*)(baseA + aOff[i]);
            bv[i] = *(const bf16x8*)(baseB + bOff[i]);
        }
        #pragma unroll
        for (int i = 0; i < 4; i++)
            #pragma unroll
            for (int j = 0; j < 4; j++)
                acc[i][j] = __builtin_amdgcn_mfma_f32_16x16x32_bf16(av[i], bv[j], acc[i][j], 0, 0, 0);
        __syncthreads();
        cur ^= 1;
    }

    #pragma unroll
    for (int i = 0; i < 4; i++){
        int gmb = row0 + wm*64 + i*16 + kc*4;
        #pragma unroll
        for (int j = 0; j < 4; j++){
            int gn = col0 + wn*64 + j*16 + fr;
            if (gn >= Nd) continue;
            #pragma unroll
            for (int r = 0; r < 4; r++){
                int gm = gmb + r;
                if (gm >= Md) continue;
                float v = alpha * acc[i][j][r];
                if (bias1) v += bias1[gn];
                if (bias2) v += bias2[(long)(gm % b2mod) * b2ld + gn];
                if (doGelu) v = gelu_exact(v);
                if (mode == 0){
                    long off = zC*sC + (long)gm*ldC + gn;
                    if (Cadd) v += Cadd[off];
                    ((float*)C)[off] = v;
                } else if (mode == 1){
                    ((bf16_t*)C)[zC*sC + (long)gm*ldC + gn] = (bf16_t)v;
                } else if (mode == 2){
                    int g = gn / 2304, w2 = gn - g*2304;
                    int hh = w2 / 192, m = w2 - hh*192;
                    int bq = gm / 196, n = gm - bq*196;
                    long slab = (long)hh*32 + bq;
                    if (g < 2)
                        ((bf16_t*)C)[(long)g*QKV_GSTRIDE + (slab*196 + n)*192 + m] = (bf16_t)v;
                    else
                        ((bf16_t*)Caux)[(slab*192 + m)*208 + n] = (bf16_t)v;
                } else {  // mode 5
                    int bq = gm / 192, m = gm - bq*192;
                    atomicAdd(&((float*)C)[((long)bq*196 + gn)*192 + m], v);
                }
            }
        }
    }
}

// ---------------- t finish: Tt[b][n][m] = bf16(TF32 + ob1[m][n]) ----------------
__global__ void __launch_bounds__(256)
t_finish_k(const float* __restrict__ tf, const float* __restrict__ ob1, bf16_t* __restrict__ tt)
{
    int idx = blockIdx.x * 256 + threadIdx.x;
    if (idx >= 1204224) return;
    int m = idx % 192;
    int n = (idx / 192) % 196;
    tt[idx] = (bf16_t)(tf[idx] + ob1[m * 196 + n]);
}

// ---------------- head: [32 x 150528] @ [150528 x 512] fp32, split-K ----------------
__global__ void __launch_bounds__(256)
head_splitk_k(const float* __restrict__ A, const float* __restrict__ W, float* __restrict__ feat)
{
    __shared__ float As[16][36];
    __shared__ float Bs[16][68];
    int col0 = blockIdx.x * 64;
    long kbase = (long)blockIdx.y * 2352;
    int tid = threadIdx.x, tx = tid & 15, ty = tid >> 4;
    float acc[2][4] = {};
    for (int k0 = 0; k0 < 2352; k0 += 16){
        #pragma unroll
        for (int u = 0; u < 2; u++){
            int idx = tid * 2 + u;
            int m = idx >> 4, kk = idx & 15;
            As[kk][m] = A[(long)m * KHEAD + kbase + k0 + kk];
        }
        #pragma unroll
        for (int u = 0; u < 4; u++){
            int idx = tid * 4 + u;
            int kk = idx >> 6, n = idx & 63;
            Bs[kk][n] = W[(kbase + k0 + kk) * 512 + col0 + n];
        }
        __syncthreads();
        #pragma unroll
        for (int kk = 0; kk < 16; kk++){
            float a0 = As[kk][ty*2], a1 = As[kk][ty*2+1];
            float b0 = Bs[kk][tx*4], b1 = Bs[kk][tx*4+1], b2 = Bs[kk][tx*4+2], b3 = Bs[kk][tx*4+3];
            acc[0][0] += a0*b0; acc[0][1] += a0*b1; acc[0][2] += a0*b2; acc[0][3] += a0*b3;
            acc[1][0] += a1*b0; acc[1][1] += a1*b1; acc[1][2] += a1*b2; acc[1][3] += a1*b3;
        }
        __syncthreads();
    }
    #pragma unroll
    for (int i = 0; i < 2; i++)
        #pragma unroll
        for (int j = 0; j < 4; j++)
            atomicAdd(&feat[(ty*2 + i) * 512 + col0 + tx*4 + j], acc[i][j]);
}

__global__ void __launch_bounds__(256)
head_finish_k(float* __restrict__ feat, const float* __restrict__ hb)
{
    int i = blockIdx.x * 256 + threadIdx.x;
    if (i < BZ * HEADU) feat[i] = gelu_exact(feat[i] + hb[i & 511]);
}

__global__ void __launch_bounds__(256)
cls_k(const float* __restrict__ feat, const float* __restrict__ W,
      const float* __restrict__ bias, float* __restrict__ out)
{
    __shared__ float fs[512];
    int b = blockIdx.y;
    int j = blockIdx.x * 256 + threadIdx.x;
    for (int i = threadIdx.x; i < 512; i += 256) fs[i] = feat[b * 512 + i];
    __syncthreads();
    if (j < NCLS){
        float s = bias[j];
        for (int k = 0; k < 512; k++) s += fs[k] * W[(long)k * NCLS + j];
        out[b * NCLS + j] = s;
    }
}

// ---------------- launch ----------------
extern "C" void kernel_launch(void* const* d_in, const int* in_sizes, int n_in,
                              void* d_out, int out_size, void* d_ws, size_t ws_size,
                              hipStream_t stream)
{
    const float* image   = (const float*)d_in[0];
    const float* patch_w = (const float*)d_in[1];
    const float* patch_b = (const float*)d_in[2];
    const float* pos_emb = (const float*)d_in[3];
    const float* qw  = (const float*)d_in[4];
    const float* qb  = (const float*)d_in[5];
    const float* kw  = (const float*)d_in[6];
    const float* kb  = (const float*)d_in[7];
    const float* vw  = (const float*)d_in[8];
    const float* vb  = (const float*)d_in[9];
    const float* ow1 = (const float*)d_in[10];
    const float* ob1 = (const float*)d_in[11];
    const float* ow2 = (const float*)d_in[12];
    const float* ob2 = (const float*)d_in[13];
    const float* d1w = (const float*)d_in[14];
    const float* d1b = (const float*)d_in[15];
    const float* d2w = (const float*)d_in[16];
    const float* d2b = (const float*)d_in[17];
    const float* head_w = (const float*)d_in[18];
    const float* head_b = (const float*)d_in[19];
    const float* cls_w  = (const float*)d_in[20];
    const float* cls_b  = (const float*)d_in[21];

    char* wsb = (char*)d_ws;
    float*  X    = (float*) (wsb + OB_X);
    float*  R    = (float*) (wsb + OB_R);
    bf16_t* XB   = (bf16_t*)(wsb + OB_XB);
    bf16_t* QKVh = (bf16_t*)(wsb + OB_QKV);
    bf16_t* VT   = (bf16_t*)(wsb + OB_VT);
    bf16_t* O    = (bf16_t*)(wsb + OB_O);
    float*  TF32 = (float*) (wsb + OB_TF32);
    bf16_t* Tt   = (bf16_t*)(wsb + OB_T);
    bf16_t* H1   = (bf16_t*)(wsb + OB_H1);
    bf16_t* PATB = H1;
    bf16_t* WQKV = (bf16_t*)(wsb + OB_WQKV);
    bf16_t* WO1  = (bf16_t*)(wsb + OB_WO1);
    bf16_t* WO2  = (bf16_t*)(wsb + OB_WO2);
    bf16_t* WD1  = (bf16_t*)(wsb + OB_WD1);
    bf16_t* WD2  = (bf16_t*)(wsb + OB_WD2);
    bf16_t* WPAT = (bf16_t*)(wsb + OB_WPAT);
    float*  BQKV = (float*) (wsb + OB_BQKV);
    float*  RSUM = (float*) (wsb + OB_RED);
    float*  RSQ  = RSUM + 1024;
    float*  STAT = (float*) (wsb + OB_STAT);
    float*  FEAT = (float*) (wsb + OB_FEAT);
    float*  out  = (float*)d_out;

    hipFuncSetAttribute((const void*)attn_fused_k,
                        hipFuncAttributeMaxDynamicSharedMemorySize, ATTN_LDS);

    auto mg = [&](const bf16_t* A, long ldA, long sA, const bf16_t* B, long ldB, long sB,
                  void* C, long ldC, long sC, void* Caux, const float* Cadd, const float* b1,
                  const float* b2, int b2mod, int b2ld,
                  int Md, int Nd, int Kd, int nb, float alpha, int gelu, int mode){
        dim3 g((Nd + 127) / 128, (Md + 127) / 128, nb);
        mfma_gemm_k<<<g, 256, 0, stream>>>(A, ldA, sA, B, ldB, sB, C, ldC, sC, Caux,
                                           Cadd, b1, b2, b2mod, b2ld,
                                           Md, Nd, Kd, alpha, gelu, mode);
    };
    auto wconv = [&](const float* in, bf16_t* o_, int IR, int IC, int perm, long OLD, int padTo){
        dim3 g((IC + 31) / 32, (padTo + 31) / 32);
        wconv_k<<<g, 256, 0, stream>>>(in, o_, IR, IC, OLD, perm, padTo);
    };
    auto layernorm = [&](const float* in, bf16_t* ob, float* of){
        reduce_k<<<1024, 256, 0, stream>>>(in, RSUM, RSQ);
        stats_k<<<1, 256, 0, stream>>>(RSUM, RSQ, STAT);
        ln_apply_k<<<4704, 256, 0, stream>>>(in, ob, of, STAT);
    };

    // ---- patch encode ----
    wconv(patch_w, WPAT, 768, 768, 0, 768, 768);
    patch_extract_k<<<18816, 256, 0, stream>>>(image, PATB);
    mg(PATB, 768, 0, WPAT, 768, 0, X, 768, 0, nullptr,
       nullptr, patch_b, pos_emb, 196, 768, 6272, 768, 768, 1, 1.f, 0, 0);
    zero_pad_o_k<<<384, 256, 0, stream>>>(O);
    vt_pad_k<<<3456, 256, 0, stream>>>(VT);

    for (int l = 0; l < NLAY; l++){
        wconv(qw + (long)l*768*2304, WQKV, 768, 2304, 1, 768, 768);
        wconv(kw + (long)l*768*2304, WQKV + 2304L*768, 768, 2304, 1, 768, 768);
        wconv(vw + (long)l*768*2304, WQKV + 4608L*768, 768, 2304, 1, 768, 768);
        gather_bias_k<<<27, 256, 0, stream>>>(qb + l*2304, kb + l*2304, vb + l*2304, BQKV);
        wconv(ow1 + (long)l*2352*196, WO1, 2352, 196, 0, 2368, 2368);
        wconv(ow2 + (long)l*192*768, WO2, 192, 768, 0, 192, 192);
        wconv(d1w + (long)l*768*3072, WD1, 768, 3072, 0, 768, 768);
        wconv(d2w + (long)l*3072*768, WD2, 3072, 768, 0, 3072, 3072);

        layernorm(X, XB, nullptr);                                   // x1
        // QKV merged -> Q/K head-major, V -> VT (transposed, padded)
        mg(XB, 768, 0, WQKV, 768, 0, QKVh, 0, 0, VT, nullptr, BQKV, nullptr, 1, 1,
           6272, 6912, 768, 1, 1.f, 0, 2);
        // fused attention -> O
        attn_fused_k<<<dim3(2, 384), 256, ATTN_LDS, stream>>>(QKVh, QKVh + QKV_GSTRIDE, VT, O);
        // t = (o @ ow1) via split-K atomics
        hipMemsetAsync(TF32, 0, 4816896, stream);
        mg(O, 2368, 0, WO1, 2368, 0, TF32, 0, 0, nullptr, nullptr, nullptr, nullptr, 1, 1,
           6144, 196, 2368, 4, 1.f, 0, 5);
        t_finish_k<<<4704, 256, 0, stream>>>(TF32, ob1 + (long)l*192*196, Tt);
        // x2 = t @ ow2 + ob2 + X -> R
        mg(Tt, 192, 0, WO2, 192, 0, R, 768, 0, nullptr, X, nullptr,
           ob2 + (long)l*196*768, 196, 768, 6272, 768, 192, 1, 1.f, 0, 0);
        layernorm(R, XB, nullptr);                                   // x3
        mg(XB, 768, 0, WD1, 768, 0, H1, 3072, 0, nullptr, nullptr, d1b + l*3072, nullptr, 1, 1,
           6272, 3072, 768, 1, 1.f, 1, 1);
        mg(H1, 3072, 0, WD2, 3072, 0, X, 768, 0, nullptr, R, d2b + l*768, nullptr, 1, 1,
           6272, 768, 3072, 1, 1.f, 1, 0);
    }

    layernorm(X, XB, R);
    hipMemsetAsync(FEAT, 0, BZ * HEADU * sizeof(float), stream);
    head_splitk_k<<<dim3(8, 64), 256, 0, stream>>>(R, head_w, FEAT);
    head_finish_k<<<64, 256, 0, stream>>>(FEAT, head_b);
    cls_k<<<dim3(4, 32), 256, 0, stream>>>(FEAT, cls_w, cls_b, out);
    (void)in_sizes; (void)n_in; (void)out_size; (void)ws_size;
}

// Round 4
// 3671.294 us; speedup vs baseline: 3.4888x; 3.4888x over previous
//
#include <hip/hip_runtime.h>
#include <cmath>

// ---------------- problem constants ----------------
#define BZ    32
#define NP    196
#define DDIM  768
#define NHEAD 12
#define MDIM  192
#define NLAY  6
#define FFDIM 3072
#define HEADU 512
#define NCLS  1000
#define KHEAD 150528      // NP*DDIM
#define BND   4816896     // BZ*NP*DDIM

typedef __bf16 bf16_t;
typedef __bf16 bf16x8 __attribute__((ext_vector_type(8)));
typedef __bf16 bf16x4 __attribute__((ext_vector_type(4)));
typedef float  f32x4  __attribute__((ext_vector_type(4)));
typedef float  f32x2  __attribute__((ext_vector_type(2)));

// ---------------- workspace layout (BYTE offsets) ----------------
#define OB_X      0L            // fp32 residual            19,267,584
#define OB_R      19267584L     // fp32 x2                  19,267,584
#define OB_XB     38535168L     // bf16 LN out               9,633,792
#define OB_XQKV   48168960L     // bf16 [6272][6912]        86,704,128  (alias: H1, PATB)
#define OB_VT     134873088L    // bf16 [384][192][208]     30,670,848
#define OB_O      165543936L    // bf16 [6144][2368]        29,097,984
#define OB_TT     194641920L    // bf16 t^T [32][192][196]   2,408,448
#define OB_T      197050368L    // bf16 t [6272][192]        2,408,448
#define OB_WQKV   199458816L    // bf16 [6912][768]         10,616,832
#define OB_WO1    210075648L    // bf16 [256][2368]          1,212,416
#define OB_WO2    211288064L    // bf16 [768][192]             294,912
#define OB_WD1    211582976L    // bf16 [3072][768]          4,718,592
#define OB_WD2    216301568L    // bf16 [768][3072]          4,718,592
#define OB_WPAT   221020160L    // bf16 [768][768]           1,179,648
#define OB_BQKV   222199808L    // fp32 [6912]
#define OB_RED    222227456L
#define OB_STAT   222235648L
#define OB_FEAT   222235904L

#define VT_SSTRIDE  39936L      // 192*208 elements per slab
#define ATTN_LDSP   93184       // P area start
#define ATTN_LDS    143360      // total dynamic LDS bytes
#define XROW        13824       // 6912*2 bytes per XQKV row

__device__ __forceinline__ float gelu_exact(float x){
    return 0.5f * x * (1.0f + erff(x * 0.70710678118654752f));
}

__device__ __forceinline__ void gld16(const void* g, void* l){
    __builtin_amdgcn_global_load_lds((const __attribute__((address_space(1))) void*)g,
                                     (__attribute__((address_space(3))) void*)l, 16, 0, 0);
}

// ---------------- patch extraction (fp32 -> bf16) ----------------
__global__ void __launch_bounds__(256)
patch_extract_k(const float* __restrict__ img, bf16_t* __restrict__ out)
{
    long idx = (long)blockIdx.x * 256 + threadIdx.x;
    if (idx >= (long)BND) return;
    int k = (int)(idx % DDIM);
    long bn = idx / DDIM;
    int n = (int)(bn % NP);
    int b = (int)(bn / NP);
    int c  = k % 3;
    int pj = (k / 3) % 16;
    int pi = k / 48;
    int gi = n / 14, gj = n % 14;
    long src = (((long)(b * 224 + gi * 16 + pi)) * 224 + (gj * 16 + pj)) * 3 + c;
    out[idx] = (bf16_t)img[src];
}

// ---------------- weight convert+transpose fp32->bf16 ----------------
__global__ void __launch_bounds__(256)
wconv_k(const float* __restrict__ in, bf16_t* __restrict__ out,
        int IR, int IC, long OLD, int perm, int padTo)
{
    __shared__ float tile[32][33];
    int tid = threadIdx.x, tx = tid & 31, ty = tid >> 5;
    int c0 = blockIdx.x * 32, r0 = blockIdx.y * 32;
    #pragma unroll
    for (int i = 0; i < 4; i++){
        int r = r0 + ty + 8*i, c = c0 + tx;
        tile[ty + 8*i][tx] = (r < IR && c < IC) ? in[(long)r * IC + c] : 0.f;
    }
    __syncthreads();
    #pragma unroll
    for (int i = 0; i < 4; i++){
        int c = c0 + ty + 8*i, r = r0 + tx;
        if (c < IC && r < padTo){
            long pc = perm ? (long)(c % 12) * 192 + c / 12 : (long)c;
            out[pc * OLD + r] = (bf16_t)tile[tx][ty + 8*i];
        }
    }
}

// ---------------- gather QKV bias into [6912] ----------------
__global__ void __launch_bounds__(256)
gather_bias_k(const float* __restrict__ qb, const float* __restrict__ kb,
              const float* __restrict__ vb, float* __restrict__ out)
{
    int tid = blockIdx.x * 256 + threadIdx.x;
    if (tid >= 6912) return;
    int g = tid / 2304, w = tid % 2304;
    int h = w / 192, m = w % 192;
    const float* src = (g == 0) ? qb : (g == 1) ? kb : vb;
    out[tid] = src[m * 12 + h];
}

// ---------------- zero O pad columns [2352,2368) ----------------
__global__ void __launch_bounds__(256)
zero_pad_o_k(bf16_t* __restrict__ o)
{
    int idx = blockIdx.x * 256 + threadIdx.x;
    if (idx >= 6144*16) return;
    int r = idx >> 4, j = idx & 15;
    o[(long)r * 2368 + 2352 + j] = (bf16_t)0.f;
}

// ---------------- V transpose: XQKV V-block -> VT [slab][192][208] (pad 0) ----
__global__ void __launch_bounds__(256)
tr_v_k(const bf16_t* __restrict__ X, bf16_t* __restrict__ VT)
{
    __shared__ bf16_t tile[32][33];
    int tid = threadIdx.x, tx = tid & 31, ty = tid >> 5;
    int s = blockIdx.z, b = s & 31, h = s >> 5;
    int m0 = blockIdx.x * 32, n0 = blockIdx.y * 32;
    #pragma unroll
    for (int i = 0; i < 4; i++){
        int r = n0 + ty + 8*i, c = m0 + tx;    // r = source n, c = m
        tile[ty + 8*i][tx] = (r < 196) ?
            X[(long)(b*196 + r) * 6912 + 4608 + h*192 + c] : (bf16_t)0.f;
    }
    __syncthreads();
    #pragma unroll
    for (int i = 0; i < 4; i++){
        int m = m0 + ty + 8*i, n = n0 + tx;
        if (n < 208)
            VT[(long)s * VT_SSTRIDE + (long)m * 208 + n] = tile[tx][ty + 8*i];
    }
}

// ---------------- t^T transpose: TT [32][192][196] -> Tt [32*196][192] -------
__global__ void __launch_bounds__(256)
tr_t_k(const bf16_t* __restrict__ TT, bf16_t* __restrict__ Tt)
{
    __shared__ bf16_t tile[32][33];
    int tid = threadIdx.x, tx = tid & 31, ty = tid >> 5;
    int b = blockIdx.z;
    int m0 = blockIdx.x * 32, n0 = blockIdx.y * 32;
    #pragma unroll
    for (int i = 0; i < 4; i++){
        int r = m0 + ty + 8*i, c = n0 + tx;    // r = m, c = n
        tile[ty + 8*i][tx] = (c < 196) ? TT[(long)b*37632 + (long)r*196 + c] : (bf16_t)0.f;
    }
    __syncthreads();
    #pragma unroll
    for (int i = 0; i < 4; i++){
        int n = n0 + ty + 8*i, m = m0 + tx;
        if (n < 196)
            Tt[((long)b*196 + n)*192 + m] = tile[tx][ty + 8*i];
    }
}

// ---------------- global layernorm ----------------
__global__ void __launch_bounds__(256)
reduce_k(const float* __restrict__ x, float* __restrict__ psum, float* __restrict__ psq)
{
    __shared__ float ss[256], sq[256];
    float s = 0.f, q = 0.f;
    const long n4 = BND / 4;
    const float4* x4 = (const float4*)x;
    for (long i = (long)blockIdx.x * 256 + threadIdx.x; i < n4; i += (long)gridDim.x * 256){
        float4 v = x4[i];
        s += v.x + v.y + v.z + v.w;
        q += v.x*v.x + v.y*v.y + v.z*v.z + v.w*v.w;
    }
    ss[threadIdx.x] = s; sq[threadIdx.x] = q;
    __syncthreads();
    for (int st = 128; st > 0; st >>= 1){
        if (threadIdx.x < st){ ss[threadIdx.x] += ss[threadIdx.x+st]; sq[threadIdx.x] += sq[threadIdx.x+st]; }
        __syncthreads();
    }
    if (threadIdx.x == 0){ psum[blockIdx.x] = ss[0]; psq[blockIdx.x] = sq[0]; }
}

__global__ void __launch_bounds__(256)
stats_k(const float* __restrict__ psum, const float* __restrict__ psq, float* __restrict__ stats)
{
    __shared__ float ss[256], sq[256];
    float s = 0.f, q = 0.f;
    for (int i = threadIdx.x; i < 1024; i += 256){ s += psum[i]; q += psq[i]; }
    ss[threadIdx.x] = s; sq[threadIdx.x] = q;
    __syncthreads();
    for (int st = 128; st > 0; st >>= 1){
        if (threadIdx.x < st){ ss[threadIdx.x] += ss[threadIdx.x+st]; sq[threadIdx.x] += sq[threadIdx.x+st]; }
        __syncthreads();
    }
    if (threadIdx.x == 0){
        float mean = ss[0] / (float)BND;
        float var  = sq[0] / (float)BND - mean * mean;
        stats[0] = mean;
        stats[1] = rsqrtf(var + 1e-6f);
    }
}

__global__ void __launch_bounds__(256)
ln_apply_k(const float* __restrict__ x, bf16_t* __restrict__ yb, float* __restrict__ yf,
           const float* __restrict__ stats)
{
    long i = (long)blockIdx.x * 256 + threadIdx.x;
    if (i >= BND / 4) return;
    float mean = stats[0], inv = stats[1];
    float4 v = ((const float4*)x)[i];
    v.x = (v.x - mean) * inv;
    v.y = (v.y - mean) * inv;
    v.z = (v.z - mean) * inv;
    v.w = (v.w - mean) * inv;
    bf16x4 o4 = { (bf16_t)v.x, (bf16_t)v.y, (bf16_t)v.z, (bf16_t)v.w };
    ((bf16x4*)yb)[i] = o4;
    if (yf) ((float4*)yf)[i] = v;
}

// ---------------- fused attention ----------------
// XQKV row-major [6272][6912]: Q cols [0,2304), K [2304,4608), V [4608,6912)
// VT [384][192][208];  O [6144][2368]: o[b*192+m][h*196+n]
__global__ void __launch_bounds__(256)
attn_fused_k(const bf16_t* __restrict__ XQKV, const bf16_t* __restrict__ VT,
             bf16_t* __restrict__ O)
{
    extern __shared__ char lds[];
    const int tid = threadIdx.x, lane = tid & 63, w = tid >> 6;
    const int fr = lane & 15, kc = lane >> 4;
    const int s = blockIdx.y, qhalf = blockIdx.x;
    const int q0 = qhalf * 112;
    const int b = s & 31, h = s >> 5;
    const float scale = 0.03608439182435161f;   // 1/sqrt(768)
    const char* Xb = (const char*)XQKV + (long)(b*196) * XROW;
    const char* Qs = Xb + h*384;
    const char* Ks = Xb + 4608 + h*384;
    const char* Vs = (const char*)(VT + (long)s * VT_SSTRIDE);

    // ---- stage K: rows n'=0..195 (384B payload in 448B LDS rows), swizzled src
    for (int t = 0; t < 23; t++){
        int idx = t*256 + tid;
        if (idx < 5824){
            int row = idx / 28, sl = idx - row*28;
            bool val = (sl < 24) && (row < 196);
            const char* src = Ks + (val ? ((long)row*XROW + ((sl*16) ^ ((row & 7) << 4))) : 0);
            gld16(src, lds + idx*16);
        }
    }
    asm volatile("s_waitcnt vmcnt(0)");
    __syncthreads();

    float pv_all[2][13][4];
    // ---- phase 1: S = Q K^T, softmax -> P in LDS
    #pragma unroll
    for (int ii = 0; ii < 2; ii++){
        int i = w + ii*4;
        if (i >= 7) continue;
        f32x4 sa[13];
        #pragma unroll
        for (int f = 0; f < 13; f++) sa[f] = (f32x4){0.f,0.f,0.f,0.f};
        int qr = q0 + i*16 + fr; if (qr > 195) qr = 195;
        #pragma unroll
        for (int c = 0; c < 6; c++){
            bf16x8 av = *(const bf16x8*)(Qs + (long)qr*XROW + c*64 + kc*16);
            #pragma unroll
            for (int f = 0; f < 13; f++){
                int krow = f*16 + fr;
                bf16x8 bv = *(const bf16x8*)(lds + krow*448 + ((c*64 + kc*16) ^ ((krow & 7) << 4)));
                sa[f] = __builtin_amdgcn_mfma_f32_16x16x32_bf16(av, bv, sa[f], 0, 0, 0);
            }
        }
        #pragma unroll
        for (int r = 0; r < 4; r++){
            float mx = -1e30f;
            #pragma unroll
            for (int f = 0; f < 13; f++)
                if (f*16 + fr < 196) mx = fmaxf(mx, sa[f][r] * scale);
            mx = fmaxf(mx, __shfl_xor(mx, 1));
            mx = fmaxf(mx, __shfl_xor(mx, 2));
            mx = fmaxf(mx, __shfl_xor(mx, 4));
            mx = fmaxf(mx, __shfl_xor(mx, 8));
            float sum = 0.f;
            #pragma unroll
            for (int f = 0; f < 13; f++){
                float pv = (f*16 + fr < 196) ? __expf(sa[f][r] * scale - mx) : 0.f;
                pv_all[ii][f][r] = pv; sum += pv;
            }
            sum += __shfl_xor(sum, 1);
            sum += __shfl_xor(sum, 2);
            sum += __shfl_xor(sum, 4);
            sum += __shfl_xor(sum, 8);
            float inv = 1.f / sum;
            #pragma unroll
            for (int f = 0; f < 13; f++) pv_all[ii][f][r] *= inv;
        }
        #pragma unroll
        for (int f = 0; f < 13; f++)
            #pragma unroll
            for (int r = 0; r < 4; r++){
                int row = i*16 + kc*4 + r;
                int cb = (f*16 + fr) * 2;
                int a = ATTN_LDSP + row*448 + (cb < 384 ? (cb ^ ((row & 7) << 4)) : cb);
                *(bf16_t*)(lds + a) = (bf16_t)pv_all[ii][f][r];
            }
        if (lane < 32){
            int row = i*16 + (lane >> 1);
            *(f32x4*)(lds + ATTN_LDSP + row*448 + 416 + (lane & 1)*16) = (f32x4){0.f,0.f,0.f,0.f};
        }
    }
    __syncthreads();

    // ---- stage V^T: rows m=0..191 (416B payload in 448B LDS rows)
    for (int t = 0; t < 21; t++){
        int idx = t*256 + tid;
        int row = idx / 28, sl = idx - row*28;
        bool val = (sl < 26);
        int cb = (sl < 24) ? ((sl*16) ^ ((row & 7) << 4)) : sl*16;
        const char* src = Vs + (val ? (row*416 + cb) : 0);
        gld16(src, lds + idx*16);
    }
    asm volatile("s_waitcnt vmcnt(0)");
    __syncthreads();

    // ---- phase 2: O = P V^T, accumulate both halves in regs
    f32x4 oa2[2][12];
    #pragma unroll
    for (int ii = 0; ii < 2; ii++){
        int i = w + ii*4;
        #pragma unroll
        for (int f = 0; f < 12; f++) oa2[ii][f] = (f32x4){0.f,0.f,0.f,0.f};
        if (i >= 7) continue;
        #pragma unroll
        for (int c = 0; c < 7; c++){
            int prow = i*16 + fr;
            int cb = c*64 + kc*16;
            int acb = (cb < 384) ? (cb ^ ((prow & 7) << 4)) : cb;
            bf16x8 av = *(const bf16x8*)(lds + ATTN_LDSP + prow*448 + acb);
            #pragma unroll
            for (int f = 0; f < 12; f++){
                int vrow = f*16 + fr;
                int bcb = (cb < 384) ? (cb ^ ((vrow & 7) << 4)) : cb;
                bf16x8 bv = *(const bf16x8*)(lds + vrow*448 + bcb);
                oa2[ii][f] = __builtin_amdgcn_mfma_f32_16x16x32_bf16(av, bv, oa2[ii][f], 0, 0, 0);
            }
        }
    }
    __syncthreads();   // all V/P reads done; reuse LDS base for O tile

    // ---- O tile -> LDS [192 rows][116 elems pitch], then coalesced copy out
    #pragma unroll
    for (int ii = 0; ii < 2; ii++){
        int i = w + ii*4;
        if (i >= 7) continue;
        #pragma unroll
        for (int f = 0; f < 12; f++){
            int m = f*16 + fr;
            #pragma unroll
            for (int r = 0; r < 4; r++){
                int nl = i*16 + kc*4 + r;
                *(bf16_t*)(lds + m*232 + nl*2) = (bf16_t)oa2[ii][f][r];
            }
        }
    }
    __syncthreads();
    const int nch = (qhalf == 0) ? 28 : 21;   // 8B chunks per row (112 or 84 cols)
    const int total = 192 * nch;
    char* ob = (char*)O + ((long)(b*192))*4736 + ((long)(h*196 + q0))*2;
    for (int idx = tid; idx < total; idx += 256){
        int m = idx / nch, ch = idx - m*nch;
        f32x2 v2 = *(const f32x2*)(lds + m*232 + ch*8);
        *(f32x2*)(ob + (long)m*4736 + ch*8) = v2;
    }
}

// ---------------- MFMA bf16 GEMM: 128x128 tile, BK=32, 4 waves ----------------
// A,B TN (k-contiguous). mode 0: f32 rowmajor (+Cadd); mode 1: bf16 rowmajor.
__global__ void __launch_bounds__(256)
mfma_gemm_k(const bf16_t* __restrict__ A, long ldA, long sA,
            const bf16_t* __restrict__ B, long ldB, long sB,
            void* __restrict__ C, long ldC, long sC,
            const float* __restrict__ Cadd,
            const float* __restrict__ bias1,
            const float* __restrict__ bias2, int b2mod, int b2ld,
            int Md, int Nd, int Kd, float alpha, int doGelu, int mode)
{
    __shared__ bf16_t sm[2][2][128][32];   // 32 KiB
    const int tid = threadIdx.x;
    const int lane = tid & 63, w = tid >> 6;
    const int wm = w >> 1, wn = w & 1;
    const int z = blockIdx.z;

    // bijective XCD-chunked swizzle over the (x,y) plane
    int n2d = gridDim.x * gridDim.y;
    int flat = blockIdx.x + gridDim.x * blockIdx.y;
    int q8 = n2d >> 3, r8 = n2d & 7;
    int xcd = flat & 7, pos = flat >> 3;
    int id2 = (xcd < r8 ? xcd*(q8+1) : r8*(q8+1) + (xcd-r8)*q8) + pos;
    int bx = id2 % gridDim.x, by = id2 / gridDim.x;

    const int row0 = by * 128, col0 = bx * 128;

    const bf16_t* Ab = A + (long)z * sA + (long)row0 * ldA;
    const bf16_t* Bb = B + (long)z * sB + (long)col0 * ldB;

    f32x4 acc[4][4];
    #pragma unroll
    for (int i = 0; i < 4; i++)
        #pragma unroll
        for (int j = 0; j < 4; j++)
            acc[i][j] = (f32x4){0.f, 0.f, 0.f, 0.f};

    const int fr = lane & 15, kc = lane >> 4;
    const int swz = (fr >> 1) & 3;
    int aOff[4], bOff[4];
    #pragma unroll
    for (int i = 0; i < 4; i++){
        aOff[i] = (wm*64 + i*16 + fr) * 64 + ((kc ^ swz) << 4);
        bOff[i] = (wn*64 + i*16 + fr) * 64 + ((kc ^ swz) << 4);
    }

    auto stage = [&](int buf, int kt){
        long kOff = (long)kt * 32;
        #pragma unroll
        for (int r = 0; r < 2; r++){
            int idx = r*256 + tid;
            int row = idx >> 2, cp = idx & 3;
            int cc = cp ^ ((row >> 1) & 3);
            gld16((const void*)(Ab + (long)row*ldA + kOff + cc*8), (void*)&sm[buf][0][row][cp*8]);
            gld16((const void*)(Bb + (long)row*ldB + kOff + cc*8), (void*)&sm[buf][1][row][cp*8]);
        }
    };

    const int nt = Kd >> 5;
    stage(0, 0);
    __syncthreads();
    int cur = 0;
    for (int t = 0; t < nt; t++){
        if (t + 1 < nt) stage(cur ^ 1, t + 1);
        const char* baseA = (const char*)sm + cur * 16384;
        const char* baseB = baseA + 8192;
        bf16x8 av[4], bv[4];
        #pragma unroll
        for (int i = 0; i < 4; i++){
            av[i] = *(const bf16x8*)(baseA + aOff[i]);
            bv[i] = *(const bf16x8*)(baseB + bOff[i]);
        }
        #pragma unroll
        for (int i = 0; i < 4; i++)
            #pragma unroll
            for (int j = 0; j < 4; j++)
                acc[i][j] = __builtin_amdgcn_mfma_f32_16x16x32_bf16(av[i], bv[j], acc[i][j], 0, 0, 0);
        __syncthreads();
        cur ^= 1;
    }

    #pragma unroll
    for (int i = 0; i < 4; i++){
        int gmb = row0 + wm*64 + i*16 + kc*4;
        #pragma unroll
        for (int j = 0; j < 4; j++){
            int gn = col0 + wn*64 + j*16 + fr;
            if (gn >= Nd) continue;
            #pragma unroll
            for (int r = 0; r < 4; r++){
                int gm = gmb + r;
                if (gm >= Md) continue;
                float v = alpha * acc[i][j][r];
                if (bias1) v += bias1[gn];
                if (bias2) v += bias2[(long)(gm % b2mod) * b2ld + gn];
                if (doGelu) v = gelu_exact(v);
                if (mode == 0){
                    long off = (long)z*sC + (long)gm*ldC + gn;
                    if (Cadd) v += Cadd[off];
                    ((float*)C)[off] = v;
                } else {
                    ((bf16_t*)C)[(long)z*sC + (long)gm*ldC + gn] = (bf16_t)v;
                }
            }
        }
    }
}

// ---------------- head: [32 x 150528] @ [150528 x 512] fp32, split-K ----------------
__global__ void __launch_bounds__(256)
head_splitk_k(const float* __restrict__ A, const float* __restrict__ W, float* __restrict__ feat)
{
    __shared__ float As[16][36];
    __shared__ float Bs[16][68];
    int col0 = blockIdx.x * 64;
    long kbase = (long)blockIdx.y * 2352;
    int tid = threadIdx.x, tx = tid & 15, ty = tid >> 4;
    float acc[2][4] = {};
    for (int k0 = 0; k0 < 2352; k0 += 16){
        #pragma unroll
        for (int u = 0; u < 2; u++){
            int idx = tid * 2 + u;
            int m = idx >> 4, kk = idx & 15;
            As[kk][m] = A[(long)m * KHEAD + kbase + k0 + kk];
        }
        #pragma unroll
        for (int u = 0; u < 4; u++){
            int idx = tid * 4 + u;
            int kk = idx >> 6, n = idx & 63;
            Bs[kk][n] = W[(kbase + k0 + kk) * 512 + col0 + n];
        }
        __syncthreads();
        #pragma unroll
        for (int kk = 0; kk < 16; kk++){
            float a0 = As[kk][ty*2], a1 = As[kk][ty*2+1];
            float b0 = Bs[kk][tx*4], b1 = Bs[kk][tx*4+1], b2 = Bs[kk][tx*4+2], b3 = Bs[kk][tx*4+3];
            acc[0][0] += a0*b0; acc[0][1] += a0*b1; acc[0][2] += a0*b2; acc[0][3] += a0*b3;
            acc[1][0] += a1*b0; acc[1][1] += a1*b1; acc[1][2] += a1*b2; acc[1][3] += a1*b3;
        }
        __syncthreads();
    }
    #pragma unroll
    for (int i = 0; i < 2; i++)
        #pragma unroll
        for (int j = 0; j < 4; j++)
            atomicAdd(&feat[(ty*2 + i) * 512 + col0 + tx*4 + j], acc[i][j]);
}

__global__ void __launch_bounds__(256)
head_finish_k(float* __restrict__ feat, const float* __restrict__ hb)
{
    int i = blockIdx.x * 256 + threadIdx.x;
    if (i < BZ * HEADU) feat[i] = gelu_exact(feat[i] + hb[i & 511]);
}

__global__ void __launch_bounds__(256)
cls_k(const float* __restrict__ feat, const float* __restrict__ W,
      const float* __restrict__ bias, float* __restrict__ out)
{
    __shared__ float fs[512];
    int b = blockIdx.y;
    int j = blockIdx.x * 256 + threadIdx.x;
    for (int i = threadIdx.x; i < 512; i += 256) fs[i] = feat[b * 512 + i];
    __syncthreads();
    if (j < NCLS){
        float s = bias[j];
        for (int k = 0; k < 512; k++) s += fs[k] * W[(long)k * NCLS + j];
        out[b * NCLS + j] = s;
    }
}

// ---------------- launch ----------------
extern "C" void kernel_launch(void* const* d_in, const int* in_sizes, int n_in,
                              void* d_out, int out_size, void* d_ws, size_t ws_size,
                              hipStream_t stream)
{
    const float* image   = (const float*)d_in[0];
    const float* patch_w = (const float*)d_in[1];
    const float* patch_b = (const float*)d_in[2];
    const float* pos_emb = (const float*)d_in[3];
    const float* qw  = (const float*)d_in[4];
    const float* qb  = (const float*)d_in[5];
    const float* kw  = (const float*)d_in[6];
    const float* kb  = (const float*)d_in[7];
    const float* vw  = (const float*)d_in[8];
    const float* vb  = (const float*)d_in[9];
    const float* ow1 = (const float*)d_in[10];
    const float* ob1 = (const float*)d_in[11];
    const float* ow2 = (const float*)d_in[12];
    const float* ob2 = (const float*)d_in[13];
    const float* d1w = (const float*)d_in[14];
    const float* d1b = (const float*)d_in[15];
    const float* d2w = (const float*)d_in[16];
    const float* d2b = (const float*)d_in[17];
    const float* head_w = (const float*)d_in[18];
    const float* head_b = (const float*)d_in[19];
    const float* cls_w  = (const float*)d_in[20];
    const float* cls_b  = (const float*)d_in[21];

    char* wsb = (char*)d_ws;
    float*  X    = (float*) (wsb + OB_X);
    float*  R    = (float*) (wsb + OB_R);
    bf16_t* XB   = (bf16_t*)(wsb + OB_XB);
    bf16_t* XQKV = (bf16_t*)(wsb + OB_XQKV);
    bf16_t* VT   = (bf16_t*)(wsb + OB_VT);
    bf16_t* O    = (bf16_t*)(wsb + OB_O);
    bf16_t* TT   = (bf16_t*)(wsb + OB_TT);
    bf16_t* Tt   = (bf16_t*)(wsb + OB_T);
    bf16_t* H1   = XQKV;            // FFN hidden aliases XQKV
    bf16_t* PATB = XQKV;            // patches alias XQKV
    bf16_t* WQKV = (bf16_t*)(wsb + OB_WQKV);
    bf16_t* WO1  = (bf16_t*)(wsb + OB_WO1);
    bf16_t* WO2  = (bf16_t*)(wsb + OB_WO2);
    bf16_t* WD1  = (bf16_t*)(wsb + OB_WD1);
    bf16_t* WD2  = (bf16_t*)(wsb + OB_WD2);
    bf16_t* WPAT = (bf16_t*)(wsb + OB_WPAT);
    float*  BQKV = (float*) (wsb + OB_BQKV);
    float*  RSUM = (float*) (wsb + OB_RED);
    float*  RSQ  = RSUM + 1024;
    float*  STAT = (float*) (wsb + OB_STAT);
    float*  FEAT = (float*) (wsb + OB_FEAT);
    float*  out  = (float*)d_out;

    hipFuncSetAttribute((const void*)attn_fused_k,
                        hipFuncAttributeMaxDynamicSharedMemorySize, ATTN_LDS);

    auto mg = [&](const bf16_t* A, long ldA, long sA, const bf16_t* B, long ldB, long sB,
                  void* C, long ldC, long sC, const float* Cadd, const float* b1,
                  const float* b2, int b2mod, int b2ld,
                  int Md, int Nd, int Kd, int nb, float alpha, int gelu, int mode){
        dim3 g((Nd + 127) / 128, (Md + 127) / 128, nb);
        mfma_gemm_k<<<g, 256, 0, stream>>>(A, ldA, sA, B, ldB, sB, C, ldC, sC,
                                           Cadd, b1, b2, b2mod, b2ld,
                                           Md, Nd, Kd, alpha, gelu, mode);
    };
    auto wconv = [&](const float* in, bf16_t* o_, int IR, int IC, int perm, long OLD, int padTo){
        dim3 g((IC + 31) / 32, (padTo + 31) / 32);
        wconv_k<<<g, 256, 0, stream>>>(in, o_, IR, IC, OLD, perm, padTo);
    };
    auto layernorm = [&](const float* in, bf16_t* ob, float* of){
        reduce_k<<<1024, 256, 0, stream>>>(in, RSUM, RSQ);
        stats_k<<<1, 256, 0, stream>>>(RSUM, RSQ, STAT);
        ln_apply_k<<<4704, 256, 0, stream>>>(in, ob, of, STAT);
    };

    // ---- patch encode ----
    wconv(patch_w, WPAT, 768, 768, 0, 768, 768);
    patch_extract_k<<<18816, 256, 0, stream>>>(image, PATB);
    mg(PATB, 768, 0, WPAT, 768, 0, X, 768, 0,
       nullptr, patch_b, pos_emb, 196, 768, 6272, 768, 768, 1, 1.f, 0, 0);
    zero_pad_o_k<<<384, 256, 0, stream>>>(O);

    for (int l = 0; l < NLAY; l++){
        wconv(qw + (long)l*768*2304, WQKV, 768, 2304, 1, 768, 768);
        wconv(kw + (long)l*768*2304, WQKV + 2304L*768, 768, 2304, 1, 768, 768);
        wconv(vw + (long)l*768*2304, WQKV + 4608L*768, 768, 2304, 1, 768, 768);
        gather_bias_k<<<27, 256, 0, stream>>>(qb + l*2304, kb + l*2304, vb + l*2304, BQKV);
        wconv(ow1 + (long)l*2352*196, WO1, 2352, 196, 0, 2368, 2368);
        wconv(ow2 + (long)l*192*768, WO2, 192, 768, 0, 192, 192);
        wconv(d1w + (long)l*768*3072, WD1, 768, 3072, 0, 768, 768);
        wconv(d2w + (long)l*3072*768, WD2, 3072, 768, 0, 3072, 3072);

        layernorm(X, XB, nullptr);                                   // x1
        // QKV: row-major [6272][6912], coalesced
        mg(XB, 768, 0, WQKV, 768, 0, XQKV, 6912, 0, nullptr, BQKV, nullptr, 1, 1,
           6272, 6912, 768, 1, 1.f, 0, 1);
        // V^T slabs
        tr_v_k<<<dim3(6, 7, 384), 256, 0, stream>>>(XQKV, VT);
        // fused attention -> O (coalesced via LDS)
        attn_fused_k<<<dim3(2, 384), 256, ATTN_LDS, stream>>>(XQKV, VT, O);
        // t^T[b][m][n] = o_b @ ow1 + ob1  (batched, coalesced bf16 write)
        mg(O, 2368, 192L*2368, WO1, 2368, 0, TT, 196, 37632, nullptr, nullptr,
           ob1 + (long)l*192*196, 192, 196, 192, 196, 2368, 32, 1.f, 0, 1);
        // transpose -> t[bn][m]
        tr_t_k<<<dim3(6, 7, 32), 256, 0, stream>>>(TT, Tt);
        // x2 = t @ ow2 + ob2 + X -> R
        mg(Tt, 192, 0, WO2, 192, 0, R, 768, 0, X, nullptr,
           ob2 + (long)l*196*768, 196, 768, 6272, 768, 192, 1, 1.f, 0, 0);
        layernorm(R, XB, nullptr);                                   // x3
        mg(XB, 768, 0, WD1, 768, 0, H1, 3072, 0, nullptr, d1b + l*3072, nullptr, 1, 1,
           6272, 3072, 768, 1, 1.f, 1, 1);
        mg(H1, 3072, 0, WD2, 3072, 0, X, 768, 0, R, d2b + l*768, nullptr, 1, 1,
           6272, 768, 3072, 1, 1.f, 1, 0);
    }

    layernorm(X, XB, R);
    hipMemsetAsync(FEAT, 0, BZ * HEADU * sizeof(float), stream);
    head_splitk_k<<<dim3(8, 64), 256, 0, stream>>>(R, head_w, FEAT);
    head_finish_k<<<64, 256, 0, stream>>>(FEAT, head_b);
    cls_k<<<dim3(4, 32), 256, 0, stream>>>(FEAT, cls_w, cls_b, out);
    (void)in_sizes; (void)n_in; (void)out_size; (void)ws_size;
}

// Round 5
// 3426.059 us; speedup vs baseline: 3.7385x; 1.0716x over previous
//
#include <hip/hip_runtime.h>
#include <cmath>

// ---------------- problem constants ----------------
#define BZ    32
#define NP    196
#define DDIM  768
#define NHEAD 12
#define MDIM  192
#define NLAY  6
#define FFDIM 3072
#define HEADU 512
#define NCLS  1000
#define KHEAD 150528      // NP*DDIM
#define BND   4816896     // BZ*NP*DDIM

typedef __bf16 bf16_t;
typedef __bf16 bf16x8 __attribute__((ext_vector_type(8)));
typedef __bf16 bf16x4 __attribute__((ext_vector_type(4)));
typedef float  f32x4  __attribute__((ext_vector_type(4)));
typedef float  f32x2  __attribute__((ext_vector_type(2)));

// ---------------- workspace layout (BYTE offsets) ----------------
#define OB_X      0L            // fp32 residual            19,267,584
#define OB_R      19267584L     // fp32 x2                  19,267,584
#define OB_XB     38535168L     // bf16 LN out               9,633,792
#define OB_XQKV   48168960L     // bf16 [6272][6912]        86,704,128  (alias: H1, PATB)
#define OB_VT     134873088L    // bf16 [384][192][208]     30,670,848
#define OB_O      165543936L    // bf16 [6144][2368]        29,097,984
#define OB_T      194641920L    // bf16 t [6272][192]        2,408,448
#define OB_WQKV   197050368L    // bf16 6 x [6912][768]     63,700,992
#define OB_WO1    260751360L    // bf16 6 x [256][2368]      7,274,496
#define OB_WO2    268025856L    // bf16 6 x [768][192]       1,769,472
#define OB_WD1    269795328L    // bf16 6 x [3072][768]     28,311,552
#define OB_WD2    298106880L    // bf16 6 x [768][3072]     28,311,552
#define OB_WPAT   326418432L    // bf16 [768][768]           1,179,648
#define OB_BQKV   327598080L    // fp32 6 x [6912]             165,888
#define OB_OB1T   327763968L    // fp32 6 x [196*192]          903,168
#define OB_RED    328667136L    // 1024 + 1024 fp32
#define OB_FEAT   328675584L    // 32*512 fp32

#define VT_SSTRIDE  39936L      // 192*208 elements per slab
#define ATTN_LDSP   93184       // P area start
#define ATTN_LDS    143360      // total dynamic LDS bytes
#define XROW        13824       // 6912*2 bytes per XQKV row

__device__ __forceinline__ float gelu_exact(float x){
    return 0.5f * x * (1.0f + erff(x * 0.70710678118654752f));
}

__device__ __forceinline__ void gld16(const void* g, void* l){
    __builtin_amdgcn_global_load_lds((const __attribute__((address_space(1))) void*)g,
                                     (__attribute__((address_space(3))) void*)l, 16, 0, 0);
}

// ---------------- patch extraction (fp32 -> bf16) ----------------
__global__ void __launch_bounds__(256)
patch_extract_k(const float* __restrict__ img, bf16_t* __restrict__ out)
{
    long idx = (long)blockIdx.x * 256 + threadIdx.x;
    if (idx >= (long)BND) return;
    int k = (int)(idx % DDIM);
    long bn = idx / DDIM;
    int n = (int)(bn % NP);
    int b = (int)(bn / NP);
    int c  = k % 3;
    int pj = (k / 3) % 16;
    int pi = k / 48;
    int gi = n / 14, gj = n % 14;
    long src = (((long)(b * 224 + gi * 16 + pi)) * 224 + (gj * 16 + pj)) * 3 + c;
    out[idx] = (bf16_t)img[src];
}

// ---------------- weight convert+transpose fp32->bf16 (layer-batched) --------
__global__ void __launch_bounds__(256)
wconv_k(const float* __restrict__ in, bf16_t* __restrict__ out,
        int IR, int IC, long OLD, int perm, int padTo, long inZ, long outZ)
{
    __shared__ float tile[32][33];
    int tid = threadIdx.x, tx = tid & 31, ty = tid >> 5;
    int c0 = blockIdx.x * 32, r0 = blockIdx.y * 32;
    const float* inz = in + (long)blockIdx.z * inZ;
    bf16_t* outz = out + (long)blockIdx.z * outZ;
    #pragma unroll
    for (int i = 0; i < 4; i++){
        int r = r0 + ty + 8*i, c = c0 + tx;
        tile[ty + 8*i][tx] = (r < IR && c < IC) ? inz[(long)r * IC + c] : 0.f;
    }
    __syncthreads();
    #pragma unroll
    for (int i = 0; i < 4; i++){
        int c = c0 + ty + 8*i, r = r0 + tx;
        if (c < IC && r < padTo){
            long pc = perm ? (long)(c % 12) * 192 + c / 12 : (long)c;
            outz[pc * OLD + r] = (bf16_t)tile[tx][ty + 8*i];
        }
    }
}

// ---------------- gather QKV bias into [6][6912] ----------------
__global__ void __launch_bounds__(256)
gather_bias_k(const float* __restrict__ qb, const float* __restrict__ kb,
              const float* __restrict__ vb, float* __restrict__ out)
{
    int tid = blockIdx.x * 256 + threadIdx.x;
    int l = blockIdx.y;
    if (tid >= 6912) return;
    int g = tid / 2304, w = tid % 2304;
    int h = w / 192, m = w % 192;
    const float* src = (g == 0) ? qb : (g == 1) ? kb : vb;
    out[l*6912 + tid] = src[l*2304 + m * 12 + h];
}

// ---------------- transpose ob1 [6][192][196] -> [6][196][192] fp32 ----------
__global__ void __launch_bounds__(256)
tr_bias_k(const float* __restrict__ ob1, float* __restrict__ out)
{
    int idx = blockIdx.x * 256 + threadIdx.x;
    int l = blockIdx.y;
    if (idx >= 37632) return;
    int n = idx / 192, m = idx - n*192;
    out[(long)l*37632 + idx] = ob1[(long)l*37632 + m*196 + n];
}

// ---------------- zero O pad columns [2352,2368) ----------------
__global__ void __launch_bounds__(256)
zero_pad_o_k(bf16_t* __restrict__ o)
{
    int idx = blockIdx.x * 256 + threadIdx.x;
    if (idx >= 6144*16) return;
    int r = idx >> 4, j = idx & 15;
    o[(long)r * 2368 + 2352 + j] = (bf16_t)0.f;
}

// ---------------- V transpose: XQKV V-block -> VT [slab][192][208] (pad 0) ----
__global__ void __launch_bounds__(256)
tr_v_k(const bf16_t* __restrict__ X, bf16_t* __restrict__ VT)
{
    __shared__ bf16_t tile[32][33];
    int tid = threadIdx.x, tx = tid & 31, ty = tid >> 5;
    int s = blockIdx.z, b = s & 31, h = s >> 5;
    int m0 = blockIdx.x * 32, n0 = blockIdx.y * 32;
    #pragma unroll
    for (int i = 0; i < 4; i++){
        int r = n0 + ty + 8*i, c = m0 + tx;    // r = source n, c = m
        tile[ty + 8*i][tx] = (r < 196) ?
            X[(long)(b*196 + r) * 6912 + 4608 + h*192 + c] : (bf16_t)0.f;
    }
    __syncthreads();
    #pragma unroll
    for (int i = 0; i < 4; i++){
        int m = m0 + ty + 8*i, n = n0 + tx;
        if (n < 208)
            VT[(long)s * VT_SSTRIDE + (long)m * 208 + n] = tile[tx][ty + 8*i];
    }
}

// ---------------- global layernorm ----------------
__global__ void __launch_bounds__(256)
reduce_k(const float* __restrict__ x, float* __restrict__ psum, float* __restrict__ psq)
{
    __shared__ float ss[256], sq[256];
    float s = 0.f, q = 0.f;
    const long n4 = BND / 4;
    const float4* x4 = (const float4*)x;
    for (long i = (long)blockIdx.x * 256 + threadIdx.x; i < n4; i += (long)gridDim.x * 256){
        float4 v = x4[i];
        s += v.x + v.y + v.z + v.w;
        q += v.x*v.x + v.y*v.y + v.z*v.z + v.w*v.w;
    }
    ss[threadIdx.x] = s; sq[threadIdx.x] = q;
    __syncthreads();
    for (int st = 128; st > 0; st >>= 1){
        if (threadIdx.x < st){ ss[threadIdx.x] += ss[threadIdx.x+st]; sq[threadIdx.x] += sq[threadIdx.x+st]; }
        __syncthreads();
    }
    if (threadIdx.x == 0){ psum[blockIdx.x] = ss[0]; psq[blockIdx.x] = sq[0]; }
}

// apply computes stats from the 1024 partials itself (no stats kernel)
__global__ void __launch_bounds__(256)
ln_apply_k(const float* __restrict__ x, bf16_t* __restrict__ yb, float* __restrict__ yf,
           const float* __restrict__ psum, const float* __restrict__ psq)
{
    __shared__ float sred[8];
    int tid = threadIdx.x;
    float s = 0.f, q = 0.f;
    for (int i = tid; i < 1024; i += 256){ s += psum[i]; q += psq[i]; }
    #pragma unroll
    for (int off = 32; off > 0; off >>= 1){ s += __shfl_xor(s, off); q += __shfl_xor(q, off); }
    if ((tid & 63) == 0){ sred[(tid>>6)*2] = s; sred[(tid>>6)*2+1] = q; }
    __syncthreads();
    s = sred[0] + sred[2] + sred[4] + sred[6];
    q = sred[1] + sred[3] + sred[5] + sred[7];
    float mean = s / (float)BND;
    float inv  = rsqrtf(q / (float)BND - mean*mean + 1e-6f);

    long i = (long)blockIdx.x * 256 + tid;
    if (i >= BND / 4) return;
    float4 v = ((const float4*)x)[i];
    v.x = (v.x - mean) * inv;
    v.y = (v.y - mean) * inv;
    v.z = (v.z - mean) * inv;
    v.w = (v.w - mean) * inv;
    bf16x4 o4 = { (bf16_t)v.x, (bf16_t)v.y, (bf16_t)v.z, (bf16_t)v.w };
    ((bf16x4*)yb)[i] = o4;
    if (yf) ((float4*)yf)[i] = v;
}

// ---------------- fused attention ----------------
__global__ void __launch_bounds__(256)
attn_fused_k(const bf16_t* __restrict__ XQKV, const bf16_t* __restrict__ VT,
             bf16_t* __restrict__ O)
{
    extern __shared__ char lds[];
    const int tid = threadIdx.x, lane = tid & 63, w = tid >> 6;
    const int fr = lane & 15, kc = lane >> 4;
    const int s = blockIdx.y, qhalf = blockIdx.x;
    const int q0 = qhalf * 112;
    const int b = s & 31, h = s >> 5;
    const float scale = 0.03608439182435161f;   // 1/sqrt(768)
    const char* Xb = (const char*)XQKV + (long)(b*196) * XROW;
    const char* Qs = Xb + h*384;
    const char* Ks = Xb + 4608 + h*384;
    const char* Vs = (const char*)(VT + (long)s * VT_SSTRIDE);

    for (int t = 0; t < 23; t++){
        int idx = t*256 + tid;
        if (idx < 5824){
            int row = idx / 28, sl = idx - row*28;
            bool val = (sl < 24) && (row < 196);
            const char* src = Ks + (val ? ((long)row*XROW + ((sl*16) ^ ((row & 7) << 4))) : 0);
            gld16(src, lds + idx*16);
        }
    }
    asm volatile("s_waitcnt vmcnt(0)");
    __syncthreads();

    float pv_all[2][13][4];
    #pragma unroll
    for (int ii = 0; ii < 2; ii++){
        int i = w + ii*4;
        if (i >= 7) continue;
        f32x4 sa[13];
        #pragma unroll
        for (int f = 0; f < 13; f++) sa[f] = (f32x4){0.f,0.f,0.f,0.f};
        int qr = q0 + i*16 + fr; if (qr > 195) qr = 195;
        #pragma unroll
        for (int c = 0; c < 6; c++){
            bf16x8 av = *(const bf16x8*)(Qs + (long)qr*XROW + c*64 + kc*16);
            #pragma unroll
            for (int f = 0; f < 13; f++){
                int krow = f*16 + fr;
                bf16x8 bv = *(const bf16x8*)(lds + krow*448 + ((c*64 + kc*16) ^ ((krow & 7) << 4)));
                sa[f] = __builtin_amdgcn_mfma_f32_16x16x32_bf16(av, bv, sa[f], 0, 0, 0);
            }
        }
        #pragma unroll
        for (int r = 0; r < 4; r++){
            float mx = -1e30f;
            #pragma unroll
            for (int f = 0; f < 13; f++)
                if (f*16 + fr < 196) mx = fmaxf(mx, sa[f][r] * scale);
            mx = fmaxf(mx, __shfl_xor(mx, 1));
            mx = fmaxf(mx, __shfl_xor(mx, 2));
            mx = fmaxf(mx, __shfl_xor(mx, 4));
            mx = fmaxf(mx, __shfl_xor(mx, 8));
            float sum = 0.f;
            #pragma unroll
            for (int f = 0; f < 13; f++){
                float pv = (f*16 + fr < 196) ? __expf(sa[f][r] * scale - mx) : 0.f;
                pv_all[ii][f][r] = pv; sum += pv;
            }
            sum += __shfl_xor(sum, 1);
            sum += __shfl_xor(sum, 2);
            sum += __shfl_xor(sum, 4);
            sum += __shfl_xor(sum, 8);
            float inv = 1.f / sum;
            #pragma unroll
            for (int f = 0; f < 13; f++) pv_all[ii][f][r] *= inv;
        }
        #pragma unroll
        for (int f = 0; f < 13; f++)
            #pragma unroll
            for (int r = 0; r < 4; r++){
                int row = i*16 + kc*4 + r;
                int cb = (f*16 + fr) * 2;
                int a = ATTN_LDSP + row*448 + (cb < 384 ? (cb ^ ((row & 7) << 4)) : cb);
                *(bf16_t*)(lds + a) = (bf16_t)pv_all[ii][f][r];
            }
        if (lane < 32){
            int row = i*16 + (lane >> 1);
            *(f32x4*)(lds + ATTN_LDSP + row*448 + 416 + (lane & 1)*16) = (f32x4){0.f,0.f,0.f,0.f};
        }
    }
    __syncthreads();

    for (int t = 0; t < 21; t++){
        int idx = t*256 + tid;
        int row = idx / 28, sl = idx - row*28;
        bool val = (sl < 26);
        int cb = (sl < 24) ? ((sl*16) ^ ((row & 7) << 4)) : sl*16;
        const char* src = Vs + (val ? (row*416 + cb) : 0);
        gld16(src, lds + idx*16);
    }
    asm volatile("s_waitcnt vmcnt(0)");
    __syncthreads();

    f32x4 oa2[2][12];
    #pragma unroll
    for (int ii = 0; ii < 2; ii++){
        int i = w + ii*4;
        #pragma unroll
        for (int f = 0; f < 12; f++) oa2[ii][f] = (f32x4){0.f,0.f,0.f,0.f};
        if (i >= 7) continue;
        #pragma unroll
        for (int c = 0; c < 7; c++){
            int prow = i*16 + fr;
            int cb = c*64 + kc*16;
            int acb = (cb < 384) ? (cb ^ ((prow & 7) << 4)) : cb;
            bf16x8 av = *(const bf16x8*)(lds + ATTN_LDSP + prow*448 + acb);
            #pragma unroll
            for (int f = 0; f < 12; f++){
                int vrow = f*16 + fr;
                int bcb = (cb < 384) ? (cb ^ ((vrow & 7) << 4)) : cb;
                bf16x8 bv = *(const bf16x8*)(lds + vrow*448 + bcb);
                oa2[ii][f] = __builtin_amdgcn_mfma_f32_16x16x32_bf16(av, bv, oa2[ii][f], 0, 0, 0);
            }
        }
    }
    __syncthreads();

    #pragma unroll
    for (int ii = 0; ii < 2; ii++){
        int i = w + ii*4;
        if (i >= 7) continue;
        #pragma unroll
        for (int f = 0; f < 12; f++){
            int m = f*16 + fr;
            #pragma unroll
            for (int r = 0; r < 4; r++){
                int nl = i*16 + kc*4 + r;
                *(bf16_t*)(lds + m*232 + nl*2) = (bf16_t)oa2[ii][f][r];
            }
        }
    }
    __syncthreads();
    const int nch = (qhalf == 0) ? 28 : 21;
    const int total = 192 * nch;
    char* ob = (char*)O + ((long)(b*192))*4736 + ((long)(h*196 + q0))*2;
    for (int idx = tid; idx < total; idx += 256){
        int m = idx / nch, ch = idx - m*nch;
        f32x2 v2 = *(const f32x2*)(lds + m*232 + ch*8);
        *(f32x2*)(ob + (long)m*4736 + ch*8) = v2;
    }
}

// ---------------- MFMA bf16 GEMM: 128x128 tile, BK=32, 4 waves ----------------
// Triple-buffered LDS, counted vmcnt across raw barriers (never drains prefetch).
// A,B TN (k-contiguous). mode 0: f32 rowmajor (+Cadd); mode 1: bf16 rowmajor.
__global__ void __launch_bounds__(256)
mfma_gemm_k(const bf16_t* __restrict__ A, long ldA, long sA,
            const bf16_t* __restrict__ B, long ldB, long sB,
            void* __restrict__ C, long ldC, long sC,
            const float* __restrict__ Cadd,
            const float* __restrict__ bias1,
            const float* __restrict__ bias2, int b2mod, int b2ld,
            int Md, int Nd, int Kd, float alpha, int doGelu, int mode)
{
    __shared__ bf16_t sm[3][2][128][32];   // 48 KiB triple-buffered
    const int tid = threadIdx.x;
    const int lane = tid & 63, w = tid >> 6;
    const int wm = w >> 1, wn = w & 1;
    const int z = blockIdx.z;

    // bijective XCD-chunked swizzle over the (x,y) plane
    int n2d = gridDim.x * gridDim.y;
    int flat = blockIdx.x + gridDim.x * blockIdx.y;
    int q8 = n2d >> 3, r8 = n2d & 7;
    int xcd = flat & 7, pos = flat >> 3;
    int id2 = (xcd < r8 ? xcd*(q8+1) : r8*(q8+1) + (xcd-r8)*q8) + pos;
    int bx = id2 % gridDim.x, by = id2 / gridDim.x;

    const int row0 = by * 128, col0 = bx * 128;

    const bf16_t* Ab = A + (long)z * sA + (long)row0 * ldA;
    const bf16_t* Bb = B + (long)z * sB + (long)col0 * ldB;

    f32x4 acc[4][4];
    #pragma unroll
    for (int i = 0; i < 4; i++)
        #pragma unroll
        for (int j = 0; j < 4; j++)
            acc[i][j] = (f32x4){0.f, 0.f, 0.f, 0.f};

    const int fr = lane & 15, kc = lane >> 4;
    const int swz = (fr >> 1) & 3;
    int aOff[4], bOff[4];
    #pragma unroll
    for (int i = 0; i < 4; i++){
        aOff[i] = (wm*64 + i*16 + fr) * 64 + ((kc ^ swz) << 4);
        bOff[i] = (wn*64 + i*16 + fr) * 64 + ((kc ^ swz) << 4);
    }

    auto stage = [&](int buf, int kt){
        long kOff = (long)kt * 32;
        #pragma unroll
        for (int r = 0; r < 2; r++){
            int idx = r*256 + tid;
            int row = idx >> 2, cp = idx & 3;
            int cc = cp ^ ((row >> 1) & 3);
            gld16((const void*)(Ab + (long)row*ldA + kOff + cc*8), (void*)&sm[buf][0][row][cp*8]);
            gld16((const void*)(Bb + (long)row*ldB + kOff + cc*8), (void*)&sm[buf][1][row][cp*8]);
        }
    };

    const int nt = Kd >> 5;
    stage(0, 0);
    stage(1, 1);
    asm volatile("s_waitcnt vmcnt(4)" ::: "memory");
    __builtin_amdgcn_s_barrier();
    __builtin_amdgcn_sched_barrier(0);

    for (int t = 0; t < nt; t++){
        int cur = t % 3;
        if (t + 2 < nt) stage((t + 2) % 3, t + 2);
        const char* baseA = (const char*)sm + cur * 16384;
        const char* baseB = baseA + 8192;
        bf16x8 av[4], bv[4];
        #pragma unroll
        for (int i = 0; i < 4; i++){
            av[i] = *(const bf16x8*)(baseA + aOff[i]);
            bv[i] = *(const bf16x8*)(baseB + bOff[i]);
        }
        __builtin_amdgcn_s_setprio(1);
        #pragma unroll
        for (int i = 0; i < 4; i++)
            #pragma unroll
            for (int j = 0; j < 4; j++)
                acc[i][j] = __builtin_amdgcn_mfma_f32_16x16x32_bf16(av[i], bv[j], acc[i][j], 0, 0, 0);
        __builtin_amdgcn_s_setprio(0);
        if (t + 2 < nt)      asm volatile("s_waitcnt vmcnt(4)" ::: "memory");
        else if (t + 1 < nt) asm volatile("s_waitcnt vmcnt(0)" ::: "memory");
        __builtin_amdgcn_s_barrier();
        __builtin_amdgcn_sched_barrier(0);
    }

    #pragma unroll
    for (int i = 0; i < 4; i++){
        int gmb = row0 + wm*64 + i*16 + kc*4;
        #pragma unroll
        for (int j = 0; j < 4; j++){
            int gn = col0 + wn*64 + j*16 + fr;
            if (gn >= Nd) continue;
            #pragma unroll
            for (int r = 0; r < 4; r++){
                int gm = gmb + r;
                if (gm >= Md) continue;
                float v = alpha * acc[i][j][r];
                if (bias1) v += bias1[gn];
                if (bias2) v += bias2[(long)(gm % b2mod) * b2ld + gn];
                if (doGelu) v = gelu_exact(v);
                if (mode == 0){
                    long off = (long)z*sC + (long)gm*ldC + gn;
                    if (Cadd) v += Cadd[off];
                    ((float*)C)[off] = v;
                } else {
                    ((bf16_t*)C)[(long)z*sC + (long)gm*ldC + gn] = (bf16_t)v;
                }
            }
        }
    }
}

// ---------------- head: [32 x 150528] @ [150528 x 512] fp32, split-K ----------------
__global__ void __launch_bounds__(256)
head_splitk_k(const float* __restrict__ A, const float* __restrict__ W, float* __restrict__ feat)
{
    __shared__ float As[16][36];
    __shared__ float Bs[16][68];
    int col0 = blockIdx.x * 64;
    long kbase = (long)blockIdx.y * 2352;
    int tid = threadIdx.x, tx = tid & 15, ty = tid >> 4;
    float acc[2][4] = {};
    for (int k0 = 0; k0 < 2352; k0 += 16){
        #pragma unroll
        for (int u = 0; u < 2; u++){
            int idx = tid * 2 + u;
            int m = idx >> 4, kk = idx & 15;
            As[kk][m] = A[(long)m * KHEAD + kbase + k0 + kk];
        }
        #pragma unroll
        for (int u = 0; u < 4; u++){
            int idx = tid * 4 + u;
            int kk = idx >> 6, n = idx & 63;
            Bs[kk][n] = W[(kbase + k0 + kk) * 512 + col0 + n];
        }
        __syncthreads();
        #pragma unroll
        for (int kk = 0; kk < 16; kk++){
            float a0 = As[kk][ty*2], a1 = As[kk][ty*2+1];
            float b0 = Bs[kk][tx*4], b1 = Bs[kk][tx*4+1], b2 = Bs[kk][tx*4+2], b3 = Bs[kk][tx*4+3];
            acc[0][0] += a0*b0; acc[0][1] += a0*b1; acc[0][2] += a0*b2; acc[0][3] += a0*b3;
            acc[1][0] += a1*b0; acc[1][1] += a1*b1; acc[1][2] += a1*b2; acc[1][3] += a1*b3;
        }
        __syncthreads();
    }
    #pragma unroll
    for (int i = 0; i < 2; i++)
        #pragma unroll
        for (int j = 0; j < 4; j++)
            atomicAdd(&feat[(ty*2 + i) * 512 + col0 + tx*4 + j], acc[i][j]);
}

__global__ void __launch_bounds__(256)
head_finish_k(float* __restrict__ feat, const float* __restrict__ hb)
{
    int i = blockIdx.x * 256 + threadIdx.x;
    if (i < BZ * HEADU) feat[i] = gelu_exact(feat[i] + hb[i & 511]);
}

__global__ void __launch_bounds__(256)
cls_k(const float* __restrict__ feat, const float* __restrict__ W,
      const float* __restrict__ bias, float* __restrict__ out)
{
    __shared__ float fs[512];
    int b = blockIdx.y;
    int j = blockIdx.x * 256 + threadIdx.x;
    for (int i = threadIdx.x; i < 512; i += 256) fs[i] = feat[b * 512 + i];
    __syncthreads();
    if (j < NCLS){
        float s = bias[j];
        for (int k = 0; k < 512; k++) s += fs[k] * W[(long)k * NCLS + j];
        out[b * NCLS + j] = s;
    }
}

// ---------------- launch ----------------
extern "C" void kernel_launch(void* const* d_in, const int* in_sizes, int n_in,
                              void* d_out, int out_size, void* d_ws, size_t ws_size,
                              hipStream_t stream)
{
    const float* image   = (const float*)d_in[0];
    const float* patch_w = (const float*)d_in[1];
    const float* patch_b = (const float*)d_in[2];
    const float* pos_emb = (const float*)d_in[3];
    const float* qw  = (const float*)d_in[4];
    const float* qb  = (const float*)d_in[5];
    const float* kw  = (const float*)d_in[6];
    const float* kb  = (const float*)d_in[7];
    const float* vw  = (const float*)d_in[8];
    const float* vb  = (const float*)d_in[9];
    const float* ow1 = (const float*)d_in[10];
    const float* ob1 = (const float*)d_in[11];
    const float* ow2 = (const float*)d_in[12];
    const float* ob2 = (const float*)d_in[13];
    const float* d1w = (const float*)d_in[14];
    const float* d1b = (const float*)d_in[15];
    const float* d2w = (const float*)d_in[16];
    const float* d2b = (const float*)d_in[17];
    const float* head_w = (const float*)d_in[18];
    const float* head_b = (const float*)d_in[19];
    const float* cls_w  = (const float*)d_in[20];
    const float* cls_b  = (const float*)d_in[21];

    char* wsb = (char*)d_ws;
    float*  X    = (float*) (wsb + OB_X);
    float*  R    = (float*) (wsb + OB_R);
    bf16_t* XB   = (bf16_t*)(wsb + OB_XB);
    bf16_t* XQKV = (bf16_t*)(wsb + OB_XQKV);
    bf16_t* VT   = (bf16_t*)(wsb + OB_VT);
    bf16_t* O    = (bf16_t*)(wsb + OB_O);
    bf16_t* Tt   = (bf16_t*)(wsb + OB_T);
    bf16_t* H1   = XQKV;
    bf16_t* PATB = XQKV;
    bf16_t* WQKV = (bf16_t*)(wsb + OB_WQKV);
    bf16_t* WO1  = (bf16_t*)(wsb + OB_WO1);
    bf16_t* WO2  = (bf16_t*)(wsb + OB_WO2);
    bf16_t* WD1  = (bf16_t*)(wsb + OB_WD1);
    bf16_t* WD2  = (bf16_t*)(wsb + OB_WD2);
    bf16_t* WPAT = (bf16_t*)(wsb + OB_WPAT);
    float*  BQKV = (float*) (wsb + OB_BQKV);
    float*  OB1T = (float*) (wsb + OB_OB1T);
    float*  RSUM = (float*) (wsb + OB_RED);
    float*  RSQ  = RSUM + 1024;
    float*  FEAT = (float*) (wsb + OB_FEAT);
    float*  out  = (float*)d_out;

    hipFuncSetAttribute((const void*)attn_fused_k,
                        hipFuncAttributeMaxDynamicSharedMemorySize, ATTN_LDS);

    auto mg = [&](const bf16_t* A, long ldA, long sA, const bf16_t* B, long ldB, long sB,
                  void* C, long ldC, long sC, const float* Cadd, const float* b1,
                  const float* b2, int b2mod, int b2ld,
                  int Md, int Nd, int Kd, int nb, float alpha, int gelu, int mode){
        dim3 g((Nd + 127) / 128, (Md + 127) / 128, nb);
        mfma_gemm_k<<<g, 256, 0, stream>>>(A, ldA, sA, B, ldB, sB, C, ldC, sC,
                                           Cadd, b1, b2, b2mod, b2ld,
                                           Md, Nd, Kd, alpha, gelu, mode);
    };
    auto wconv = [&](const float* in, bf16_t* o_, int IR, int IC, int perm, long OLD,
                     int padTo, int nz, long inZ, long outZ){
        dim3 g((IC + 31) / 32, (padTo + 31) / 32, nz);
        wconv_k<<<g, 256, 0, stream>>>(in, o_, IR, IC, OLD, perm, padTo, inZ, outZ);
    };
    auto layernorm = [&](const float* in, bf16_t* ob, float* of){
        reduce_k<<<1024, 256, 0, stream>>>(in, RSUM, RSQ);
        ln_apply_k<<<4704, 256, 0, stream>>>(in, ob, of, RSUM, RSQ);
    };

    // ---- bulk weight conversion (all layers upfront) ----
    wconv(patch_w, WPAT, 768, 768, 0, 768, 768, 1, 0, 0);
    wconv(qw, WQKV,               768, 2304, 1, 768, 768, 6, 768L*2304, 6912L*768);
    wconv(kw, WQKV + 2304L*768,   768, 2304, 1, 768, 768, 6, 768L*2304, 6912L*768);
    wconv(vw, WQKV + 4608L*768,   768, 2304, 1, 768, 768, 6, 768L*2304, 6912L*768);
    wconv(ow1, WO1, 2352, 196, 0, 2368, 2368, 6, 2352L*196, 606208L);
    wconv(ow2, WO2, 192, 768, 0, 192, 192, 6, 147456L, 147456L);
    wconv(d1w, WD1, 768, 3072, 0, 768, 768, 6, 2359296L, 2359296L);
    wconv(d2w, WD2, 3072, 768, 0, 3072, 3072, 6, 2359296L, 2359296L);
    gather_bias_k<<<dim3(27, 6), 256, 0, stream>>>(qb, kb, vb, BQKV);
    tr_bias_k<<<dim3(147, 6), 256, 0, stream>>>(ob1, OB1T);

    // ---- patch encode ----
    patch_extract_k<<<18816, 256, 0, stream>>>(image, PATB);
    mg(PATB, 768, 0, WPAT, 768, 0, X, 768, 0,
       nullptr, patch_b, pos_emb, 196, 768, 6272, 768, 768, 1, 1.f, 0, 0);
    zero_pad_o_k<<<384, 256, 0, stream>>>(O);

    for (int l = 0; l < NLAY; l++){
        layernorm(X, XB, nullptr);                                   // x1
        // QKV: row-major [6272][6912]
        mg(XB, 768, 0, WQKV + (long)l*6912*768, 768, 0, XQKV, 6912, 0, nullptr,
           BQKV + l*6912, nullptr, 1, 1, 6272, 6912, 768, 1, 1.f, 0, 1);
        tr_v_k<<<dim3(6, 7, 384), 256, 0, stream>>>(XQKV, VT);
        attn_fused_k<<<dim3(2, 384), 256, ATTN_LDS, stream>>>(XQKV, VT, O);
        // t[b][n][m] = ow1^T_n . o_b_m + ob1^T  (direct, coalesced)
        mg(WO1 + (long)l*606208, 2368, 0, O, 2368, 192L*2368, Tt, 192, 37632,
           nullptr, nullptr, OB1T + (long)l*37632, 196, 192,
           196, 192, 2368, 32, 1.f, 0, 1);
        // x2 = t @ ow2 + ob2 + X -> R
        mg(Tt, 192, 0, WO2 + (long)l*147456, 192, 0, R, 768, 0, X, nullptr,
           ob2 + (long)l*196*768, 196, 768, 6272, 768, 192, 1, 1.f, 0, 0);
        layernorm(R, XB, nullptr);                                   // x3
        mg(XB, 768, 0, WD1 + (long)l*2359296, 768, 0, H1, 3072, 0, nullptr,
           d1b + l*3072, nullptr, 1, 1, 6272, 3072, 768, 1, 1.f, 1, 1);
        mg(H1, 3072, 0, WD2 + (long)l*2359296, 3072, 0, X, 768, 0, R,
           d2b + l*768, nullptr, 1, 1, 6272, 768, 3072, 1, 1.f, 1, 0);
    }

    layernorm(X, XB, R);
    hipMemsetAsync(FEAT, 0, BZ * HEADU * sizeof(float), stream);
    head_splitk_k<<<dim3(8, 64), 256, 0, stream>>>(R, head_w, FEAT);
    head_finish_k<<<64, 256, 0, stream>>>(FEAT, head_b);
    cls_k<<<dim3(4, 32), 256, 0, stream>>>(FEAT, cls_w, cls_b, out);
    (void)in_sizes; (void)n_in; (void)out_size; (void)ws_size;
}